// Round 6
// baseline (1072.480 us; speedup 1.0000x reference)
//
#include <hip/hip_runtime.h>
#include <hip/hip_cooperative_groups.h>

namespace cg = cooperative_groups;

#define T 8192
#define D 1024
#define E 64
#define CAP 256

typedef float f32x4 __attribute__((ext_vector_type(4)));

#define TEC ((size_t)134217728)            // T*E*CAP
#define C_OFF   ((size_t)1)
#define M_OFF   ((size_t)1 + TEC)
#define CNT_OFF ((size_t)1 + 2 * TEC)

// Fused gate + histogram + prefix + rank + patch, one cooperative kernel.
// Phase 1 (all 512 blocks): R5's verified gate for 16 tokens/block; per-block
//   histogram + Sg partials land in LDS, then NON-ATOMIC per-block global
//   slots (bcb/sgb) — no pre-zeroed global accumulators, so no ws memset.
// Phase 2a (blocks 0..31): reduce 16 sub-bins -> per-chunk bc32/sgc.
// Phase 2b (blocks 0..31): R4/R5's verified ballot-rank + patch; block 31
//   writes expert_counts and l_aux.
__global__ __launch_bounds__(256) void kfused(
    const float* __restrict__ x, const float* __restrict__ Wred,
    const float* __restrict__ cent, int* __restrict__ idx1,
    float* __restrict__ g15, int* __restrict__ bcb, float* __restrict__ sgb,
    int* __restrict__ bc32, float* __restrict__ sgc, float* __restrict__ out)
{
    __shared__ float wcol[4 * D];   // column-major: wcol[c*D + d]
    __shared__ float cn[E * 4];
    __shared__ float sg[E];
    __shared__ int   hh[E];
    const int tid = threadIdx.x;
    const int bid = blockIdx.x;

    // ---------------- phase 1: gate 16 tokens ----------------
    for (int i = tid; i < 4 * D; i += 256) {
        int d = i >> 2, c = i & 3;
        wcol[c * D + d] = Wred[i];
    }
    if (tid < E) {
        float c0 = cent[tid * 4 + 0];
        float c1 = cent[tid * 4 + 1];
        float c2 = cent[tid * 4 + 2];
        float c3 = cent[tid * 4 + 3];
        float n = fmaxf(sqrtf(c0 * c0 + c1 * c1 + c2 * c2 + c3 * c3), 1e-4f);
        cn[tid * 4 + 0] = c0 / n;
        cn[tid * 4 + 1] = c1 / n;
        cn[tid * 4 + 2] = c2 / n;
        cn[tid * 4 + 3] = c3 / n;
        sg[tid] = 0.0f;
        hh[tid] = 0;
    }
    __syncthreads();

    const f32x4* __restrict__ wc4 = (const f32x4*)wcol;   // [4][256] f32x4
    const int wave = tid >> 6, lane = tid & 63;
    for (int it = 0; it < 4; ++it) {               // 512 blocks * 4 iters * 4 waves = 8192 tokens
        const int t = bid * 16 + it * 4 + wave;
        const f32x4* __restrict__ xr4 = (const f32x4*)(x + (size_t)t * D);
        float a0 = 0.f, a1 = 0.f, a2 = 0.f, a3 = 0.f;
        #pragma unroll
        for (int k = 0; k < 4; ++k) {
            const int i = k * 64 + lane;           // f32x4 index: 16B/lane, coalesced
            const f32x4 xv = xr4[i];
            const f32x4 w0 = wc4[0 * 256 + i];
            const f32x4 w1 = wc4[1 * 256 + i];
            const f32x4 w2 = wc4[2 * 256 + i];
            const f32x4 w3 = wc4[3 * 256 + i];
            a0 += xv[0] * w0[0] + xv[1] * w0[1] + xv[2] * w0[2] + xv[3] * w0[3];
            a1 += xv[0] * w1[0] + xv[1] * w1[1] + xv[2] * w1[2] + xv[3] * w1[3];
            a2 += xv[0] * w2[0] + xv[1] * w2[1] + xv[2] * w2[2] + xv[3] * w2[3];
            a3 += xv[0] * w3[0] + xv[1] * w3[1] + xv[2] * w3[2] + xv[3] * w3[3];
        }
        #pragma unroll
        for (int off = 32; off; off >>= 1) {       // xor-butterfly: all lanes get full sums
            a0 += __shfl_xor(a0, off);
            a1 += __shfl_xor(a1, off);
            a2 += __shfl_xor(a2, off);
            a3 += __shfl_xor(a3, off);
        }
        float logit = a0 * cn[lane * 4 + 0] + a1 * cn[lane * 4 + 1]
                    + a2 * cn[lane * 4 + 2] + a3 * cn[lane * 4 + 3];
        float m = logit;
        #pragma unroll
        for (int off = 32; off; off >>= 1) m = fmaxf(m, __shfl_xor(m, off));
        unsigned long long ball = __ballot(logit == m);
        int amax = __ffsll(ball) - 1;              // first-occurrence argmax (matches jnp)
        float ev = expf(logit - m);
        float s = ev;
        #pragma unroll
        for (int off = 32; off; off >>= 1) s += __shfl_xor(s, off);
        atomicAdd(&sg[lane], ev / s);              // LDS Sg partial, distinct addr per lane
        if (lane == 0) {
            idx1[t] = amax;
            g15[t] = 1.5f / s;                     // gate at argmax = 1/s
            atomicAdd(&hh[amax], 1);               // LDS per-block histogram
        }
    }
    __syncthreads();
    if (tid < E) {                                 // non-atomic per-block slots
        bcb[bid * E + tid] = hh[tid];
        sgb[bid * E + tid] = sg[tid];
    }

    __threadfence();
    cg::this_grid().sync();

    // ---------------- phase 2a: 32 blocks reduce 16 sub-bins ----------------
    if (bid < 32 && tid < E) {
        int   s1 = 0;
        float s2 = 0.f;
        #pragma unroll
        for (int j = 0; j < 16; ++j) {
            s1 += bcb[(bid * 16 + j) * E + tid];
            s2 += sgb[(bid * 16 + j) * E + tid];
        }
        bc32[bid * E + tid] = s1;                  // per-chunk histogram
        sgc [bid * E + tid] = s2;                  // per-chunk Sg partial
    }
    __threadfence();
    cg::this_grid().sync();

    // ---------------- phase 2b: 32 blocks rank + patch ----------------
    if (bid < 32) {
        __shared__ int pfe[E];
        __shared__ int cwf[256];                   // cwf[w*64+e]: count of e in wave w
        const int chunk = bid;
        const int t2 = chunk * 256 + tid;
        const int e = idx1[t2];

        if (tid < E) {
            int run = 0;
            for (int b = 0; b < chunk; ++b) run += bc32[b * E + tid];
            pfe[tid] = run;                        // tokens of expert `tid` in earlier chunks
        }
        cwf[tid] = 0;
        __syncthreads();

        unsigned long long same = ~0ull;           // lanes in my wave with same expert
        #pragma unroll
        for (int b = 0; b < 6; ++b) {
            unsigned long long bal = __ballot(((e >> b) & 1) != 0);
            same &= ((e >> b) & 1) ? bal : ~bal;
        }
        const unsigned long long below = ((unsigned long long)1 << lane) - 1ull;
        const int rank_in_wave = __popcll(same & below);
        if ((same & below) == 0ull) cwf[wave * E + e] = __popcll(same);  // wave leader
        __syncthreads();

        int rank = pfe[e] + rank_in_wave;
        if (wave > 0) rank += cwf[0 * E + e];
        if (wave > 1) rank += cwf[1 * E + e];
        if (wave > 2) rank += cwf[2 * E + e];

        if (rank < CAP) {
            const size_t row = (size_t)t2 * (E * CAP) + (size_t)e * CAP + rank;
            out[C_OFF + row] = g15[t2];            // combine value (1.5 * max gate, > 0)
            out[M_OFF + row] = 1.0f;               // dispatch_mask
        }

        if (chunk == 31 && tid < E) {              // totals, counts, l_aux
            int total = pfe[tid] + bc32[31 * E + tid];
            out[CNT_OFF + tid] = (float)total;     // expert_counts (pre-capacity)
            float S = 0.f;
            #pragma unroll
            for (int c2 = 0; c2 < 32; ++c2) S += sgc[c2 * E + tid];
            float v = S * (float)total;
            #pragma unroll
            for (int off = 32; off; off >>= 1) v += __shfl_xor(v, off);
            if (tid == 0) out[0] = v * ((float)E / ((float)T * (float)T));  // 64/2^26 exact
        }
    }
}

extern "C" void kernel_launch(void* const* d_in, const int* in_sizes, int n_in,
                              void* d_out, int out_size, void* d_ws, size_t ws_size,
                              hipStream_t stream)
{
    const float* x    = (const float*)d_in[0];   // [T, D]
    const float* Wred = (const float*)d_in[1];   // [D, 4]
    const float* cent = (const float*)d_in[2];   // [E, 4]
    float* out = (float*)d_out;

    char* ws = (char*)d_ws;                      // ~344 KB used, no zeroing needed
    int*   idx1 = (int*)ws;                      // T ints
    float* g15  = (float*)(ws + 32768);          // T floats
    int*   bcb  = (int*)(ws + 65536);            // 512*64 ints  (per-block hist)
    float* sgb  = (float*)(ws + 65536 + 131072); // 512*64 floats (per-block Sg)
    int*   bc32 = (int*)(ws + 65536 + 262144);   // 32*64 ints   (per-chunk hist)
    float* sgc  = (float*)(ws + 65536 + 262144 + 8192);  // 32*64 floats

    // Output fill via rocclr memset (6.2 TB/s measured; in-kernel fills ran
    // ~3 TB/s in R3/R4 — falsified). out_size is in BYTES.
    (void)hipMemsetAsync(d_out, 0, (size_t)out_size, stream);

    void* args[] = {(void*)&x, (void*)&Wred, (void*)&cent, (void*)&idx1,
                    (void*)&g15, (void*)&bcb, (void*)&sgb, (void*)&bc32,
                    (void*)&sgc, (void*)&out};
    (void)hipLaunchCooperativeKernel((void*)kfused, dim3(512), dim3(256),
                                     args, 0, stream);
}

// Round 7
// 987.223 us; speedup vs baseline: 1.0864x; 1.0864x over previous
//
#include <hip/hip_runtime.h>

#define T 8192
#define D 1024
#define E 64
#define CAP 256

typedef float f32x4 __attribute__((ext_vector_type(4)));

#define TEC ((size_t)134217728)            // T*E*CAP
#define C_OFF   ((size_t)1)
#define M_OFF   ((size_t)1 + TEC)
#define CNT_OFF ((size_t)1 + 2 * TEC)

// K1: one wave per token (512 blocks x 16 tokens — proven shape). f32x4
// global/LDS loads. Per-block histogram + Sg partials go to NON-ATOMIC
// per-block global slots bcb/sgb (no pre-zeroed accumulators -> the ws
// memset dispatch is gone; k1 has zero global atomics). Sg accumulation is
// per-lane registers + one LDS wave-reduce (no LDS atomics on the Sg path).
__global__ __launch_bounds__(256) void k1_gate(
    const float* __restrict__ x, const float* __restrict__ Wred,
    const float* __restrict__ cent, int* __restrict__ idx1,
    float* __restrict__ g15, int* __restrict__ bcb, float* __restrict__ sgb)
{
    __shared__ float wcol[4 * D];   // column-major: wcol[c*D + d]
    __shared__ float cn[E * 4];
    __shared__ float sgw[4 * E];    // per-wave Sg partials
    __shared__ int   hh[E];
    const int tid = threadIdx.x;
    const int bid = blockIdx.x;

    for (int i = tid; i < 4 * D; i += 256) {
        int d = i >> 2, c = i & 3;
        wcol[c * D + d] = Wred[i];
    }
    if (tid < E) {
        float c0 = cent[tid * 4 + 0];
        float c1 = cent[tid * 4 + 1];
        float c2 = cent[tid * 4 + 2];
        float c3 = cent[tid * 4 + 3];
        float n = fmaxf(sqrtf(c0 * c0 + c1 * c1 + c2 * c2 + c3 * c3), 1e-4f);
        cn[tid * 4 + 0] = c0 / n;
        cn[tid * 4 + 1] = c1 / n;
        cn[tid * 4 + 2] = c2 / n;
        cn[tid * 4 + 3] = c3 / n;
        hh[tid] = 0;
    }
    __syncthreads();

    const f32x4* __restrict__ wc4 = (const f32x4*)wcol;   // [4][256] f32x4
    const int wave = tid >> 6, lane = tid & 63;
    float sgacc = 0.f;                              // this lane's expert partial
    for (int it = 0; it < 4; ++it) {               // 512 blocks * 4 iters * 4 waves = 8192 tokens
        const int t = bid * 16 + it * 4 + wave;
        const f32x4* __restrict__ xr4 = (const f32x4*)(x + (size_t)t * D);
        float a0 = 0.f, a1 = 0.f, a2 = 0.f, a3 = 0.f;
        #pragma unroll
        for (int k = 0; k < 4; ++k) {
            const int i = k * 64 + lane;           // f32x4 index: 16B/lane, coalesced
            const f32x4 xv = xr4[i];
            const f32x4 w0 = wc4[0 * 256 + i];
            const f32x4 w1 = wc4[1 * 256 + i];
            const f32x4 w2 = wc4[2 * 256 + i];
            const f32x4 w3 = wc4[3 * 256 + i];
            a0 += xv[0] * w0[0] + xv[1] * w0[1] + xv[2] * w0[2] + xv[3] * w0[3];
            a1 += xv[0] * w1[0] + xv[1] * w1[1] + xv[2] * w1[2] + xv[3] * w1[3];
            a2 += xv[0] * w2[0] + xv[1] * w2[1] + xv[2] * w2[2] + xv[3] * w2[3];
            a3 += xv[0] * w3[0] + xv[1] * w3[1] + xv[2] * w3[2] + xv[3] * w3[3];
        }
        #pragma unroll
        for (int off = 32; off; off >>= 1) {       // xor-butterfly: all lanes get full sums
            a0 += __shfl_xor(a0, off);
            a1 += __shfl_xor(a1, off);
            a2 += __shfl_xor(a2, off);
            a3 += __shfl_xor(a3, off);
        }
        float logit = a0 * cn[lane * 4 + 0] + a1 * cn[lane * 4 + 1]
                    + a2 * cn[lane * 4 + 2] + a3 * cn[lane * 4 + 3];
        float m = logit;
        #pragma unroll
        for (int off = 32; off; off >>= 1) m = fmaxf(m, __shfl_xor(m, off));
        unsigned long long ball = __ballot(logit == m);
        int amax = __ffsll(ball) - 1;              // first-occurrence argmax (matches jnp)
        float ev = expf(logit - m);
        float s = ev;
        #pragma unroll
        for (int off = 32; off; off >>= 1) s += __shfl_xor(s, off);
        sgacc += ev / s;                           // gates[t][lane] accumulated in register
        if (lane == 0) {
            idx1[t] = amax;
            g15[t] = 1.5f / s;                     // gate at argmax = 1/s
            atomicAdd(&hh[amax], 1);               // LDS hist (16 atomics/block total)
        }
    }
    sgw[wave * E + lane] = sgacc;
    __syncthreads();
    if (tid < E) {                                 // non-atomic per-block slots
        bcb[bid * E + tid] = hh[tid];
        sgb[bid * E + tid] = sgw[tid] + sgw[E + tid] + sgw[2 * E + tid] + sgw[3 * E + tid];
    }
}

// k5: per-chunk prefix + rank + patch (ballot-rank verified R4/R5). The
// per-expert prefix now sums the 512 per-block sub-bins directly (k1's
// 16-blocks-per-chunk layout: chunk c covers blocks [16c, 16c+16)).
// Block 31 writes expert_counts and l_aux (Sg totals from sgb).
__global__ __launch_bounds__(256) void k5_prefix_patch(
    const int* __restrict__ idx1, const float* __restrict__ g15,
    const int* __restrict__ bcb, const float* __restrict__ sgb,
    float* __restrict__ out)
{
    __shared__ int pfe[E];
    __shared__ int cwf[256];                       // cwf[w*64+e]: count of e in wave w
    const int tid = threadIdx.x;
    const int chunk = blockIdx.x;
    const int t = chunk * 256 + tid;
    const int e = idx1[t];

    if (tid < E) {
        int run = 0;
        for (int b = 0; b < chunk * 16; ++b) run += bcb[b * E + tid];
        pfe[tid] = run;                            // tokens of expert `tid` in earlier chunks
    }
    cwf[tid] = 0;
    __syncthreads();

    const int wave = tid >> 6, lane = tid & 63;
    unsigned long long same = ~0ull;               // lanes in my wave with same expert
    #pragma unroll
    for (int b = 0; b < 6; ++b) {
        unsigned long long bal = __ballot(((e >> b) & 1) != 0);
        same &= ((e >> b) & 1) ? bal : ~bal;
    }
    const unsigned long long below = ((unsigned long long)1 << lane) - 1ull;
    const int rank_in_wave = __popcll(same & below);
    if ((same & below) == 0ull) cwf[wave * E + e] = __popcll(same);  // wave leader
    __syncthreads();

    int rank = pfe[e] + rank_in_wave;
    if (wave > 0) rank += cwf[0 * E + e];
    if (wave > 1) rank += cwf[1 * E + e];
    if (wave > 2) rank += cwf[2 * E + e];

    if (rank < CAP) {
        const size_t row = (size_t)t * (E * CAP) + (size_t)e * CAP + rank;
        out[C_OFF + row] = g15[t];                 // combine value (1.5 * max gate, > 0)
        out[M_OFF + row] = 1.0f;                   // dispatch_mask
    }

    if (chunk == 31 && tid < E) {                  // totals, counts, l_aux
        int total = pfe[tid];
        #pragma unroll
        for (int b = 496; b < 512; ++b) total += bcb[b * E + tid];
        out[CNT_OFF + tid] = (float)total;         // expert_counts (pre-capacity)
        float S = 0.f;
        for (int b = 0; b < 512; ++b) S += sgb[b * E + tid];
        float v = S * (float)total;
        #pragma unroll
        for (int off = 32; off; off >>= 1) v += __shfl_xor(v, off);
        if (tid == 0) out[0] = v * ((float)E / ((float)T * (float)T));  // 64/2^26 exact
    }
}

extern "C" void kernel_launch(void* const* d_in, const int* in_sizes, int n_in,
                              void* d_out, int out_size, void* d_ws, size_t ws_size,
                              hipStream_t stream)
{
    const float* x    = (const float*)d_in[0];   // [T, D]
    const float* Wred = (const float*)d_in[1];   // [D, 4]
    const float* cent = (const float*)d_in[2];   // [E, 4]
    float* out = (float*)d_out;

    char* ws = (char*)d_ws;                      // 320 KB used, no zeroing needed
    int*   idx1 = (int*)ws;                      // T ints
    float* g15  = (float*)(ws + 32768);          // T floats
    int*   bcb  = (int*)(ws + 65536);            // 512*64 ints   (per-block hist)
    float* sgb  = (float*)(ws + 65536 + 131072); // 512*64 floats (per-block Sg)

    // Output fill via rocclr memset (6.2 TB/s; in-kernel fills ran ~3 TB/s
    // in R3/R4 — falsified; cooperative fusion cost +140 us in R6 —
    // falsified). out_size is in BYTES. 3 stream ops total.
    (void)hipMemsetAsync(d_out, 0, (size_t)out_size, stream);

    k1_gate<<<512, 256, 0, stream>>>(x, Wred, cent, idx1, g15, bcb, sgb);
    k5_prefix_patch<<<32, 256, 0, stream>>>(idx1, g15, bcb, sgb, out);
}

// Round 9
// 933.422 us; speedup vs baseline: 1.1490x; 1.0576x over previous
//
#include <hip/hip_runtime.h>

#define T 8192
#define D 1024
#define E 64
#define CAP 256

typedef float f32x4 __attribute__((ext_vector_type(4)));

#define TEC ((size_t)134217728)            // T*E*CAP
#define C_OFF   ((size_t)1)
#define M_OFF   ((size_t)1 + TEC)
#define CNT_OFF ((size_t)1 + 2 * TEC)

// K1: one wave per token (512 blocks x 16 tokens — R1/R5's proven shape).
// red = x_row @ W_red with f32x4 global loads (16B/lane) and ds_read_b128
// LDS reads; logits vs normalized centroids (lane = expert), softmax +
// first-index argmax. Fuses the per-chunk expert histogram (bc) — one
// atomicAdd per token; bc pre-zeroed by the 8.4-KB ws memset.
// [R7 falsified replacing these atomics with 512-slot non-atomic bins:
//  it moved reduction cost into the 32-block k5 (+55 us).]
__global__ __launch_bounds__(256) void k1_gate(
    const float* __restrict__ x, const float* __restrict__ Wred,
    const float* __restrict__ cent, int* __restrict__ idx1,
    float* __restrict__ g15, float* __restrict__ Sg, int* __restrict__ bc)
{
    __shared__ float wcol[4 * D];   // column-major: wcol[c*D + d]
    __shared__ float cn[E * 4];
    __shared__ float sg[E];
    const int tid = threadIdx.x;

    for (int i = tid; i < 4 * D; i += 256) {
        int d = i >> 2, c = i & 3;
        wcol[c * D + d] = Wred[i];
    }
    if (tid < E) {
        float c0 = cent[tid * 4 + 0];
        float c1 = cent[tid * 4 + 1];
        float c2 = cent[tid * 4 + 2];
        float c3 = cent[tid * 4 + 3];
        float n = fmaxf(sqrtf(c0 * c0 + c1 * c1 + c2 * c2 + c3 * c3), 1e-4f);
        cn[tid * 4 + 0] = c0 / n;
        cn[tid * 4 + 1] = c1 / n;
        cn[tid * 4 + 2] = c2 / n;
        cn[tid * 4 + 3] = c3 / n;
        sg[tid] = 0.0f;
    }
    __syncthreads();

    const f32x4* __restrict__ wc4 = (const f32x4*)wcol;   // [4][256] f32x4
    const int wave = tid >> 6, lane = tid & 63;
    for (int it = 0; it < 4; ++it) {               // 512 blocks * 4 iters * 4 waves = 8192 tokens
        const int t = blockIdx.x * 16 + it * 4 + wave;
        const f32x4* __restrict__ xr4 = (const f32x4*)(x + (size_t)t * D);
        float a0 = 0.f, a1 = 0.f, a2 = 0.f, a3 = 0.f;
        #pragma unroll
        for (int k = 0; k < 4; ++k) {
            const int i = k * 64 + lane;           // f32x4 index: 16B/lane, coalesced
            const f32x4 xv = xr4[i];
            const f32x4 w0 = wc4[0 * 256 + i];
            const f32x4 w1 = wc4[1 * 256 + i];
            const f32x4 w2 = wc4[2 * 256 + i];
            const f32x4 w3 = wc4[3 * 256 + i];
            a0 += xv[0] * w0[0] + xv[1] * w0[1] + xv[2] * w0[2] + xv[3] * w0[3];
            a1 += xv[0] * w1[0] + xv[1] * w1[1] + xv[2] * w1[2] + xv[3] * w1[3];
            a2 += xv[0] * w2[0] + xv[1] * w2[1] + xv[2] * w2[2] + xv[3] * w2[3];
            a3 += xv[0] * w3[0] + xv[1] * w3[1] + xv[2] * w3[2] + xv[3] * w3[3];
        }
        #pragma unroll
        for (int off = 32; off; off >>= 1) {       // xor-butterfly: all lanes get full sums
            a0 += __shfl_xor(a0, off);
            a1 += __shfl_xor(a1, off);
            a2 += __shfl_xor(a2, off);
            a3 += __shfl_xor(a3, off);
        }
        float logit = a0 * cn[lane * 4 + 0] + a1 * cn[lane * 4 + 1]
                    + a2 * cn[lane * 4 + 2] + a3 * cn[lane * 4 + 3];
        float m = logit;
        #pragma unroll
        for (int off = 32; off; off >>= 1) m = fmaxf(m, __shfl_xor(m, off));
        unsigned long long ball = __ballot(logit == m);
        int amax = __ffsll(ball) - 1;              // first-occurrence argmax (matches jnp)
        float ev = expf(logit - m);
        float s = ev;
        #pragma unroll
        for (int off = 32; off; off >>= 1) s += __shfl_xor(s, off);
        atomicAdd(&sg[lane], ev / s);              // Sg partial, distinct addr per lane
        if (lane == 0) {
            idx1[t] = amax;
            g15[t] = 1.5f / s;                     // gate at argmax = 1/s
            atomicAdd(&bc[(t >> 8) * E + amax], 1); // chunk histogram (fused k2)
        }
    }
    __syncthreads();
    if (tid < E) atomicAdd(&Sg[tid], sg[tid]);
}

// k5: per-chunk prefix + rank + patch (verified R4/R5). 32 blocks x 256
// (block = 256-token chunk). pf computed inline from bc. Within-chunk rank
// via expert-bit ballot matching (6 ballots) + cross-wave LDS counts.
// Block 31 additionally writes expert_counts and l_aux.
__global__ __launch_bounds__(256) void k5_prefix_patch(
    const int* __restrict__ idx1, const float* __restrict__ g15,
    const int* __restrict__ bc, const float* __restrict__ Sg,
    float* __restrict__ out)
{
    __shared__ int pfe[E];
    __shared__ int cwf[256];                       // cwf[w*64+e]: count of e in wave w
    const int tid = threadIdx.x;
    const int chunk = blockIdx.x;
    const int t = chunk * 256 + tid;
    const int e = idx1[t];

    if (tid < E) {
        int run = 0;
        for (int b = 0; b < chunk; ++b) run += bc[b * E + tid];
        pfe[tid] = run;                            // tokens of expert `tid` in earlier chunks
    }
    cwf[tid] = 0;
    __syncthreads();

    const int wave = tid >> 6, lane = tid & 63;
    unsigned long long same = ~0ull;               // lanes in my wave with same expert
    #pragma unroll
    for (int b = 0; b < 6; ++b) {
        unsigned long long bal = __ballot(((e >> b) & 1) != 0);
        same &= ((e >> b) & 1) ? bal : ~bal;
    }
    const unsigned long long below = ((unsigned long long)1 << lane) - 1ull;
    const int rank_in_wave = __popcll(same & below);
    if ((same & below) == 0ull) cwf[wave * E + e] = __popcll(same);  // wave leader
    __syncthreads();

    int rank = pfe[e] + rank_in_wave;
    if (wave > 0) rank += cwf[0 * E + e];
    if (wave > 1) rank += cwf[1 * E + e];
    if (wave > 2) rank += cwf[2 * E + e];

    if (rank < CAP) {
        const size_t row = (size_t)t * (E * CAP) + (size_t)e * CAP + rank;
        out[C_OFF + row] = g15[t];                 // combine value (1.5 * max gate, > 0)
        out[M_OFF + row] = 1.0f;                   // dispatch_mask
    }

    if (chunk == 31 && tid < E) {                  // totals, counts, l_aux
        int total = pfe[tid] + bc[31 * E + tid];
        out[CNT_OFF + tid] = (float)total;         // expert_counts (pre-capacity)
        float v = Sg[tid] * (float)total;
        #pragma unroll
        for (int off = 32; off; off >>= 1) v += __shfl_xor(v, off);
        if (tid == 0) out[0] = v * ((float)E / ((float)T * (float)T));  // 64/2^26 exact
    }
}

extern "C" void kernel_launch(void* const* d_in, const int* in_sizes, int n_in,
                              void* d_out, int out_size, void* d_ws, size_t ws_size,
                              hipStream_t stream)
{
    const float* x    = (const float*)d_in[0];   // [T, D]
    const float* Wred = (const float*)d_in[1];   // [D, 4]
    const float* cent = (const float*)d_in[2];   // [E, 4]
    float* out = (float*)d_out;

    char* ws = (char*)d_ws;
    int*   idx1 = (int*)ws;                      // T ints
    float* g15  = (float*)(ws + 32768);          // T floats
    float* Sg   = (float*)(ws + 65536);          // 64 floats   (zeroed)
    int*   bc   = (int*)(ws + 65536 + 256);      // 32*64 ints  (zeroed, k1 accumulates)

    // Output fill via rocclr memset (6.2 TB/s measured). Falsified
    // alternatives: in-kernel fills ~3 TB/s (R3/R4), cooperative fusion
    // +140 us (R6), fine-grained non-atomic accumulators +55 us (R7).
    // out_size is in BYTES.
    (void)hipMemsetAsync(d_out, 0, (size_t)out_size, stream);
    (void)hipMemsetAsync(Sg, 0, 256 + 32 * E * sizeof(int), stream);

    k1_gate<<<512, 256, 0, stream>>>(x, Wred, cent, idx1, g15, Sg, bc);
    k5_prefix_patch<<<32, 256, 0, stream>>>(idx1, g15, bc, Sg, out);
}